// Round 5
// baseline (468.404 us; speedup 1.0000x reference)
//
#include <hip/hip_runtime.h>
#include <cstdint>
#include <cstddef>

typedef unsigned short u16;
typedef __attribute__((ext_vector_type(8))) short short8;
typedef __attribute__((ext_vector_type(8))) u16 ushort8;
typedef __attribute__((ext_vector_type(4))) float float4_t;

#define BB 8
#define NN 8192
#define DD 64
#define NTILES 64            // 8192 / 128 column tiles (pre_kernel format)
#define TILE_SHORTS 8192     // 128 points * 64 k (bf16)
#define LDS_STRIDE 68        // 64 floats + 4 pad (bank spread)

__device__ inline u16 f32_to_bf16(float f) {
  unsigned u = __float_as_uint(f);
  u += 0x7FFFu + ((u >> 16) & 1u);   // RNE
  return (u16)(u >> 16);
}

__device__ inline unsigned enc_ord(float f) {
  unsigned u = __float_as_uint(f);
  return (u & 0x80000000u) ? ~u : (u | 0x80000000u);
}
__device__ inline float dec_ord(unsigned u) {
  return __uint_as_float((u & 0x80000000u) ? (u & 0x7fffffffu) : ~u);
}

// ---------------------------------------------------------------------------
// K1: one block = one 128x64 tile. Coalesced read-once -> LDS -> swizzled
// bf16 tile (MFMA fragment chunk order) + 0.5*|row|^2. Zeroes out[] and, in
// the fallback path, the ordered-uint max buffers.  [verified R6/R7 — UNCHANGED]
// Chunk layout per tile: [I(8)][s(2)] chunks of 1KB; within a chunk lane
// l (l=qq*16+rl) holds point I*16+rl, k = s*32+qq*8+j (j=0..7, 16B).
// ---------------------------------------------------------------------------
__global__ __launch_bounds__(256) void pre_kernel(
    const float* __restrict__ x, const float* __restrict__ y,
    u16* __restrict__ xs, u16* __restrict__ ys,
    float* __restrict__ x2h, float* __restrict__ y2h,
    unsigned* __restrict__ rowmax_u, unsigned* __restrict__ colmax_u,
    float* __restrict__ out, const int use_part)
{
  __shared__ float stage[128 * LDS_STRIDE];   // 34 KB

  const int bid = blockIdx.x;          // 1024: 0..511 -> x, 512..1023 -> y
  const int tid = threadIdx.x;

  if (!use_part) {
    if (bid < 256)      colmax_u[(bid << 8) | tid] = 0u;
    else if (bid < 512) rowmax_u[((bid - 256) << 8) | tid] = 0u;
  }
  if (bid == 0 && tid == 0) out[0] = 0.f;

  const bool isY = bid >= 512;
  const int t = bid & 511;             // tile id = b*64 + nt
  const float* src = (isY ? y : x) + (size_t)t * (128 * DD);
  u16* dst = (isY ? ys : xs) + (size_t)t * TILE_SHORTS;
  float* s2 = (isY ? y2h : x2h) + t * 128;

#pragma unroll
  for (int c = 0; c < 8; ++c) {
    const int idx = c * 256 + tid;     // float4 index within tile (0..2047)
    float4 f = ((const float4*)src)[idx];
    const int r = idx >> 4, kc = idx & 15;
    *(float4*)&stage[r * LDS_STRIDE + kc * 4] = f;
  }
  __syncthreads();

  {
    const int r = tid >> 1, half = tid & 1;
    const float* rp = &stage[r * LDS_STRIDE + half * 32];
    float ss = 0.f;
#pragma unroll
    for (int k = 0; k < 8; ++k) {
      float4 f = *(const float4*)&rp[k * 4];
      ss += f.x*f.x + f.y*f.y + f.z*f.z + f.w*f.w;
    }
    ss += __shfl_xor(ss, 1);
    if (half == 0) s2[r] = 0.5f * ss;
  }

  {
    const int w = tid >> 6, lane = tid & 63;
    const int qq = lane >> 4, rl = lane & 15;
#pragma unroll
    for (int u = 0; u < 4; ++u) {
      const int chunk = w * 4 + u;
      const int I = chunk >> 1, s = chunk & 1;
      const float* rp = &stage[(I*16 + rl) * LDS_STRIDE + s*32 + qq*8];
      ushort8 o;
#pragma unroll
      for (int j = 0; j < 8; ++j) o[j] = f32_to_bf16(rp[j]);
      *(ushort8*)(dst + chunk*512 + lane*8) = o;
    }
  }
}

// ---------------------------------------------------------------------------
// K2: main — R13.  R12 post-mortem: launch_bounds(256,3) with grid 1024
// (= 4 blocks/CU of work) runs TWO PHASES: 768 blocks at 3/CU then 256 at
// 1/CU -> time-avg occupancy (3+1)/2 = 2 blocks/CU = 25% (measured 24.6%)
// and wall time ~2x per-block time. Neither pipe saturated (MfmaUtil 29,
// true-VALU ~30; VALUBusy counter lumps both).
// R13 = R12 verbatim + two changes:
//   1. launch_bounds(256,4): grid 1024 = EXACTLY 4 blocks/CU resident ->
//      single phase, no tail. Safe now: R12's ping-pong state measures
//      84 VGPR < the 128-reg cap (R10's spill was a ~124-reg state with
//      Bf[4][2]=32 live). LDS 4 x 33.8 KB = 135 < 160 KB. Spill tripwire:
//      WRITE_SIZE must stay 16.9 MB.
//   2. col-max tree reshaped into max3-fusable triples (15 -> 8 VALU/jj).
// R3/R4/R6/R8 bans respected: C-init carries -x2/2, jj-sequential acc.
// ---------------------------------------------------------------------------
__global__ __launch_bounds__(256, 4) void main_kernel(
    const u16* __restrict__ xs, const u16* __restrict__ ys,
    const float* __restrict__ x2h, const float* __restrict__ y2h,
    float* __restrict__ rowpart, float* __restrict__ colpart,
    unsigned* __restrict__ rowmax_u, unsigned* __restrict__ colmax_u,
    const int use_part)
{
  __shared__ float colbuf[2][4096];    // 32 KB: [wr][mt*128 + col]
  __shared__ float rowbuf[2][128];     // [wc][row]

  const int bid = blockIdx.x;            // 1024
  const int b   = bid & 7;               // XCD-affine
  const int nt  = (bid >> 3) & 63;
  const int h   = bid >> 9;              // column half
  const int tid = threadIdx.x;
  const int w = tid >> 6, lane = tid & 63;
  const int wr = w >> 1, wc = w & 1;     // row-half / col-half owner
  const int l15 = lane & 15, q = lane >> 4;
  const int n0 = nt << 7;
  const int mt_start = h << 5;           // 32 col-tiles per block

  // ---- A fragments: this wave's 64 rows, both K-halves ----
  const u16* xs_tile = xs + (size_t)((b << 6) | nt) * TILE_SHORTS;
  short8 afr[4][2];
#pragma unroll
  for (int i = 0; i < 4; ++i)
#pragma unroll
    for (int s = 0; s < 2; ++s)
      afr[i][s] = *(const short8*)(xs_tile + ((wr*4 + i)*2 + s)*512 + lane*8);

  // ---- C-init quads: -x2/2 per row (fp32 exact) ----
  float4_t negx2[4];
  const float* x2b = x2h + b*NN + n0 + wr*64;
#pragma unroll
  for (int i = 0; i < 4; ++i) {
    float4_t v = *(const float4_t*)(x2b + i*16 + q*4);
    negx2[i] = {-v[0], -v[1], -v[2], -v[3]};
  }

  float rowmax[4][4];
#pragma unroll
  for (int i = 0; i < 4; ++i)
#pragma unroll
    for (int r = 0; r < 4; ++r) rowmax[i][r] = -3.0e38f;

  // ---- pointer-bumped streams; imm offsets cover the chunk loads ----
  const u16*  pB = ys + (size_t)((b << 6) + mt_start) * TILE_SHORTS
                   + wc*4096 + lane*8;
  const float* pY = y2h + b*NN + mt_start*128 + wc*64 + l15;

  // ---- ping-pong B pipeline: prologue fills buffer A (mt=0, jj=0) ----
  short8 bA0, bA1, bB0, bB1;
  float  y2A, y2B;
  bA0 = *(const short8*)(pB);
  bA1 = *(const short8*)(pB + 512);
  y2A = pY[0];

  int moff = 0;
  for (int mt = 0; mt < 32; ++mt) {
    // STEP(JJ): compute with (C0,C1,YC) = fragment-pair JJ of tile mt,
    // prefetch (N0,N1,YN) = the NEXT fragment pair (next tile at JJ=3).
#define CHAM_STEP(JJ, NOFF, NY, C0, C1, YC, N0, N1, YN)                       \
    {                                                                         \
      N0 = *(const short8*)(pB + (NOFF));                                     \
      N1 = *(const short8*)(pB + (NOFF) + 512);                               \
      YN = pY[(NY)];                                                          \
      /* acc = xy - x2/2 (C carries exact fp32 -x2/2) */                      \
      float4_t acc[4];                                                        \
      acc[0] = __builtin_amdgcn_mfma_f32_16x16x32_bf16(afr[0][0], C0, negx2[0], 0, 0, 0); \
      acc[1] = __builtin_amdgcn_mfma_f32_16x16x32_bf16(afr[1][0], C0, negx2[1], 0, 0, 0); \
      acc[2] = __builtin_amdgcn_mfma_f32_16x16x32_bf16(afr[2][0], C0, negx2[2], 0, 0, 0); \
      acc[3] = __builtin_amdgcn_mfma_f32_16x16x32_bf16(afr[3][0], C0, negx2[3], 0, 0, 0); \
      acc[0] = __builtin_amdgcn_mfma_f32_16x16x32_bf16(afr[0][1], C1, acc[0], 0, 0, 0);   \
      acc[1] = __builtin_amdgcn_mfma_f32_16x16x32_bf16(afr[1][1], C1, acc[1], 0, 0, 0);   \
      acc[2] = __builtin_amdgcn_mfma_f32_16x16x32_bf16(afr[2][1], C1, acc[2], 0, 0, 0);   \
      acc[3] = __builtin_amdgcn_mfma_f32_16x16x32_bf16(afr[3][1], C1, acc[3], 0, 0, 0);   \
      /* col side: max3-fusable triples: 16 values in 8 v_max3/v_max */       \
      float t0 = fmaxf(fmaxf(acc[0][0], acc[0][1]), acc[0][2]);               \
      float t1 = fmaxf(fmaxf(acc[0][3], acc[1][0]), acc[1][1]);               \
      float t2 = fmaxf(fmaxf(acc[1][2], acc[1][3]), acc[2][0]);               \
      float t3 = fmaxf(fmaxf(acc[2][1], acc[2][2]), acc[2][3]);               \
      float t4 = fmaxf(fmaxf(acc[3][0], acc[3][1]), acc[3][2]);               \
      float u0 = fmaxf(fmaxf(t0, t1), t2);                                    \
      float u1 = fmaxf(fmaxf(t3, t4), acc[3][3]);                             \
      float cm = fmaxf(u0, u1);                                               \
      cm = fmaxf(cm, __shfl_xor(cm, 16));                                     \
      cm = fmaxf(cm, __shfl_xor(cm, 32));                                     \
      if (q == 0)                                                             \
        colbuf[wr][moff + wc*64 + (JJ)*16 + l15] = cm;                        \
      /* row side: rowmax = max(acc - y2/2) = -min(d^2)/2 */                  \
      {                                                                       \
        const float y2j = YC;                                                 \
        for (int i_ = 0; i_ < 4; ++i_)                                        \
          for (int r_ = 0; r_ < 4; ++r_)                                      \
            rowmax[i_][r_] = fmaxf(rowmax[i_][r_], acc[i_][r_] - y2j);        \
      }                                                                       \
    }
    CHAM_STEP(0, 1024,        16,  bA0, bA1, y2A, bB0, bB1, y2B)
    CHAM_STEP(1, 2048,        32,  bB0, bB1, y2B, bA0, bA1, y2A)
    CHAM_STEP(2, 3072,        48,  bA0, bA1, y2A, bB0, bB1, y2B)
    CHAM_STEP(3, TILE_SHORTS, 128, bB0, bB1, y2B, bA0, bA1, y2A)
#undef CHAM_STEP
    pB += TILE_SHORTS;
    pY += 128;
    moff += 128;
  }

  // ---- row side finalize: shfl over cols (l15), cross-wc via LDS ----
#pragma unroll
  for (int i = 0; i < 4; ++i)
#pragma unroll
    for (int r = 0; r < 4; ++r) {
      float v = rowmax[i][r];
      v = fmaxf(v, __shfl_xor(v, 1));
      v = fmaxf(v, __shfl_xor(v, 2));
      v = fmaxf(v, __shfl_xor(v, 4));
      v = fmaxf(v, __shfl_xor(v, 8));
      rowmax[i][r] = v;
    }
  if (l15 == 0) {
#pragma unroll
    for (int i = 0; i < 4; ++i)
#pragma unroll
      for (int r = 0; r < 4; ++r)
        rowbuf[wc][wr*64 + i*16 + q*4 + r] = rowmax[i][r];
  }
  __syncthreads();   // colbuf planes + rowbuf complete

  if (tid < 128) {
    float v = fmaxf(rowbuf[0][tid], rowbuf[1][tid]);     // -min(d^2)/2
    if (use_part) rowpart[(size_t)((h << 9) | (b << 6) | nt) * 128 + tid] = v;
    else          atomicMax(&rowmax_u[b*NN + n0 + tid], enc_ord(v));
  }

  // ---- col drain: fold wr planes; 16 KB coalesced stores (partial path) ----
  {
    float*    colp = colpart + (size_t)((b << 6) | nt) * NN + (h << 12);
    unsigned* colu = colmax_u + b*NN + (h << 12);
#pragma unroll
    for (int k = 0; k < 16; ++k) {
      const int t = k * 256 + tid;
      const float m = fmaxf(colbuf[0][t], colbuf[1][t]);
      if (use_part) colp[t] = m;
      else          atomicMax(&colu[t], enc_ord(m));
    }
  }
}

// ---------------------------------------------------------------------------
// K3: col combine over 64 nt + sqrt; row combine over 2 h + sqrt; block sum;
// atomicAdd scaled result into out.  [R0 version verbatim]
// ---------------------------------------------------------------------------
__global__ __launch_bounds__(256) void reduce_kernel(
    const float* __restrict__ rowpart, const float* __restrict__ colpart,
    const unsigned* __restrict__ rowmax_u, const unsigned* __restrict__ colmax_u,
    const float* __restrict__ y2h, float* __restrict__ out,
    const int use_part)
{
  const int bid = blockIdx.x;          // 256
  const int tid = threadIdx.x;
  const int g = bid*256 + tid;         // 0..65535
  const int b = g >> 13, m = g & (NN - 1);

  float vc, vr;
  if (use_part) {
    vc = -3.0e38f;
#pragma unroll 8
    for (int nt = 0; nt < 64; ++nt)
      vc = fmaxf(vc, colpart[(size_t)((b << 6) | nt) * NN + m]);
    const int nt = m >> 7, r = m & 127;
    float r0 = rowpart[(size_t)((0 << 9) | (b << 6) | nt) * 128 + r];
    float r1 = rowpart[(size_t)((1 << 9) | (b << 6) | nt) * 128 + r];
    vr = fmaxf(r0, r1);
  } else {
    vc = dec_ord(colmax_u[g]);
    vr = dec_ord(rowmax_u[g]);
  }
  float s = sqrtf(fmaxf(2.f*(y2h[g] - vc), 0.f))   // nearest-x for this y
          + sqrtf(fmaxf(-2.f*vr, 0.f));            // nearest-y for this x

#pragma unroll
  for (int d = 1; d < 64; d <<= 1) s += __shfl_xor(s, d);
  __shared__ float wsum[4];
  if ((tid & 63) == 0) wsum[tid >> 6] = s;
  __syncthreads();
  if (tid == 0)
    atomicAdd(out, (wsum[0] + wsum[1] + wsum[2] + wsum[3]) * (1.0f / 65536.0f));
}

// ---------------------------------------------------------------------------
extern "C" void kernel_launch(void* const* d_in, const int* in_sizes, int n_in,
                              void* d_out, int out_size, void* d_ws, size_t ws_size,
                              hipStream_t stream) {
  const float* x = (const float*)d_in[0];
  const float* y = (const float*)d_in[1];
  float* out = (float*)d_out;

  char* p = (char*)d_ws;
  u16* xs = (u16*)p;            p += (size_t)512 * 16384;   // 8 MiB
  u16* ys = (u16*)p;            p += (size_t)512 * 16384;   // 8 MiB
  float* x2h = (float*)p;       p += (size_t)65536 * 4;
  float* y2h = (float*)p;       p += (size_t)65536 * 4;
  char* tail = p;
  // partial path: colpart 16 MiB + rowpart 512 KiB  (33 MiB total — proven
  // to fit in R0; R9's 49 MiB overflowed and fell back to atomics)
  float* colpart = (float*)tail;
  float* rowpart = (float*)(tail + (size_t)512 * 8192 * 4);
  // atomic fallback: two 256 KiB ordered-uint max buffers
  unsigned* colmax_u = (unsigned*)tail;
  unsigned* rowmax_u = (unsigned*)(tail + (size_t)65536 * 4);
  const size_t need_part = (size_t)(tail - (char*)d_ws) +
                           (size_t)512 * 8192 * 4 + (size_t)1024 * 128 * 4;
  const int use_part = (ws_size >= need_part) ? 1 : 0;

  pre_kernel<<<dim3(1024), dim3(256), 0, stream>>>(x, y, xs, ys, x2h, y2h,
                                                   rowmax_u, colmax_u, out,
                                                   use_part);
  main_kernel<<<dim3(1024), dim3(256), 0, stream>>>(xs, ys, x2h, y2h,
                                                    rowpart, colpart,
                                                    rowmax_u, colmax_u,
                                                    use_part);
  reduce_kernel<<<dim3(256), dim3(256), 0, stream>>>(rowpart, colpart,
                                                     rowmax_u, colmax_u, y2h,
                                                     out, use_part);
}

// Round 6
// 181.400 us; speedup vs baseline: 2.5822x; 2.5822x over previous
//
#include <hip/hip_runtime.h>
#include <cstdint>
#include <cstddef>

typedef unsigned short u16;
typedef __attribute__((ext_vector_type(8))) short short8;
typedef __attribute__((ext_vector_type(8))) u16 ushort8;
typedef __attribute__((ext_vector_type(4))) float float4_t;

#define BB 8
#define NN 8192
#define DD 64
#define NTILES 64            // 8192 / 128 column tiles (pre_kernel format)
#define TILE_SHORTS 8192     // 128 points * 64 k (bf16)
#define LDS_STRIDE 68        // 64 floats + 4 pad (bank spread)

__device__ inline u16 f32_to_bf16(float f) {
  unsigned u = __float_as_uint(f);
  u += 0x7FFFu + ((u >> 16) & 1u);   // RNE
  return (u16)(u >> 16);
}

__device__ inline unsigned enc_ord(float f) {
  unsigned u = __float_as_uint(f);
  return (u & 0x80000000u) ? ~u : (u | 0x80000000u);
}
__device__ inline float dec_ord(unsigned u) {
  return __uint_as_float((u & 0x80000000u) ? (u & 0x7fffffffu) : ~u);
}

// ---------------------------------------------------------------------------
// K1: one block = one 128x64 tile. Coalesced read-once -> LDS -> swizzled
// bf16 tile (MFMA fragment chunk order) + 0.5*|row|^2. Zeroes out[] and, in
// the fallback path, the ordered-uint max buffers.  [verified R6/R7 — UNCHANGED]
// Chunk layout per tile: [I(8)][s(2)] chunks of 1KB; within a chunk lane
// l (l=qq*16+rl) holds point I*16+rl, k = s*32+qq*8+j (j=0..7, 16B).
// ---------------------------------------------------------------------------
__global__ __launch_bounds__(256) void pre_kernel(
    const float* __restrict__ x, const float* __restrict__ y,
    u16* __restrict__ xs, u16* __restrict__ ys,
    float* __restrict__ x2h, float* __restrict__ y2h,
    unsigned* __restrict__ rowmax_u, unsigned* __restrict__ colmax_u,
    float* __restrict__ out, const int use_part)
{
  __shared__ float stage[128 * LDS_STRIDE];   // 34 KB

  const int bid = blockIdx.x;          // 1024: 0..511 -> x, 512..1023 -> y
  const int tid = threadIdx.x;

  if (!use_part) {
    if (bid < 256)      colmax_u[(bid << 8) | tid] = 0u;
    else if (bid < 512) rowmax_u[((bid - 256) << 8) | tid] = 0u;
  }
  if (bid == 0 && tid == 0) out[0] = 0.f;

  const bool isY = bid >= 512;
  const int t = bid & 511;             // tile id = b*64 + nt
  const float* src = (isY ? y : x) + (size_t)t * (128 * DD);
  u16* dst = (isY ? ys : xs) + (size_t)t * TILE_SHORTS;
  float* s2 = (isY ? y2h : x2h) + t * 128;

#pragma unroll
  for (int c = 0; c < 8; ++c) {
    const int idx = c * 256 + tid;     // float4 index within tile (0..2047)
    float4 f = ((const float4*)src)[idx];
    const int r = idx >> 4, kc = idx & 15;
    *(float4*)&stage[r * LDS_STRIDE + kc * 4] = f;
  }
  __syncthreads();

  {
    const int r = tid >> 1, half = tid & 1;
    const float* rp = &stage[r * LDS_STRIDE + half * 32];
    float ss = 0.f;
#pragma unroll
    for (int k = 0; k < 8; ++k) {
      float4 f = *(const float4*)&rp[k * 4];
      ss += f.x*f.x + f.y*f.y + f.z*f.z + f.w*f.w;
    }
    ss += __shfl_xor(ss, 1);
    if (half == 0) s2[r] = 0.5f * ss;
  }

  {
    const int w = tid >> 6, lane = tid & 63;
    const int qq = lane >> 4, rl = lane & 15;
#pragma unroll
    for (int u = 0; u < 4; ++u) {
      const int chunk = w * 4 + u;
      const int I = chunk >> 1, s = chunk & 1;
      const float* rp = &stage[(I*16 + rl) * LDS_STRIDE + s*32 + qq*8];
      ushort8 o;
#pragma unroll
      for (int j = 0; j < 8; ++j) o[j] = f32_to_bf16(rp[j]);
      *(ushort8*)(dst + chunk*512 + lane*8) = o;
    }
  }
}

// ---------------------------------------------------------------------------
// K2: main — R14.  Session ledger:
//   R0  90us: 1x4 split, FULL-tile prefetch, (256,2), ~184 regs, occ 18.8%
//   R12 100us: 2x2 split, QUARTER-tile prefetch, (256,3), 84 VGPR, occ 24.6%
//   R10/R13: launch_bounds(256,4) = POISON (allocator targets 64 VGPR ->
//            300 MB scratch traffic). Never request 4 waves/EU.
// R12 beat R0 on occupancy but lost on per-wave stalls: its prefetch
// distance (8 MFMA ~ 155 cyc) < L2 latency (~200-300 cyc). R0's full-tile
// distance (~900 cyc) hid loads completely. R14 combines the winners:
// 2x2 split (small state) + DEPTH-2 jj-granular pipeline via 4-buffer
// rotation: step jj consumes buf[jj], loads buf[(jj+2)&3] -> issue-to-use
// distance 2 steps ~ 500 cyc > L2 latency. All buffer names static (rule
// #20). ~128-reg estimate at (256,3): spill-free; if allocator lands <=128
// the HW fits 4 blocks/CU naturally (LB is a floor for regalloc, not a
// residency cap). s_setprio(1) around the MFMA cluster: in-loop waves are
// barrier-free/independent (the attn-like +4-7% regime, not lockstep null).
// Final prefetches over-read <=1.25KB past ys into x2h (mapped) — never
// consumed, safe.
// R3/R4/R6/R8 bans respected: C-init carries -x2/2, jj-sequential acc.
// ---------------------------------------------------------------------------
__global__ __launch_bounds__(256, 3) void main_kernel(
    const u16* __restrict__ xs, const u16* __restrict__ ys,
    const float* __restrict__ x2h, const float* __restrict__ y2h,
    float* __restrict__ rowpart, float* __restrict__ colpart,
    unsigned* __restrict__ rowmax_u, unsigned* __restrict__ colmax_u,
    const int use_part)
{
  __shared__ float colbuf[2][4096];    // 32 KB: [wr][mt*128 + col]
  __shared__ float rowbuf[2][128];     // [wc][row]

  const int bid = blockIdx.x;            // 1024
  const int b   = bid & 7;               // XCD-affine
  const int nt  = (bid >> 3) & 63;
  const int h   = bid >> 9;              // column half
  const int tid = threadIdx.x;
  const int w = tid >> 6, lane = tid & 63;
  const int wr = w >> 1, wc = w & 1;     // row-half / col-half owner
  const int l15 = lane & 15, q = lane >> 4;
  const int n0 = nt << 7;
  const int mt_start = h << 5;           // 32 col-tiles per block

  // ---- A fragments: this wave's 64 rows, both K-halves ----
  const u16* xs_tile = xs + (size_t)((b << 6) | nt) * TILE_SHORTS;
  short8 afr[4][2];
#pragma unroll
  for (int i = 0; i < 4; ++i)
#pragma unroll
    for (int s = 0; s < 2; ++s)
      afr[i][s] = *(const short8*)(xs_tile + ((wr*4 + i)*2 + s)*512 + lane*8);

  // ---- C-init quads: -x2/2 per row (fp32 exact) ----
  float4_t negx2[4];
  const float* x2b = x2h + b*NN + n0 + wr*64;
#pragma unroll
  for (int i = 0; i < 4; ++i) {
    float4_t v = *(const float4_t*)(x2b + i*16 + q*4);
    negx2[i] = {-v[0], -v[1], -v[2], -v[3]};
  }

  float rowmax[4][4];
#pragma unroll
  for (int i = 0; i < 4; ++i)
#pragma unroll
    for (int r = 0; r < 4; ++r) rowmax[i][r] = -3.0e38f;

  // ---- pointer-bumped streams; imm offsets cover the chunk loads ----
  const u16*  pB = ys + (size_t)((b << 6) + mt_start) * TILE_SHORTS
                   + wc*4096 + lane*8;
  const float* pY = y2h + b*NN + mt_start*128 + wc*64 + l15;

  // ---- depth-2 pipeline, 4 static buffers: step jj consumes bJJ, loads
  //      b[(jj+2)&3]. Prologue fills b0 (tile0,jj0) and b1 (tile0,jj1). ----
  short8 b0lo, b0hi, b1lo, b1hi, b2lo, b2hi, b3lo, b3hi;
  float  y20, y21, y22, y23;
  b0lo = *(const short8*)(pB);
  b0hi = *(const short8*)(pB + 512);
  y20  = pY[0];
  b1lo = *(const short8*)(pB + 1024);
  b1hi = *(const short8*)(pB + 1536);
  y21  = pY[16];

  int moff = 0;
  for (int mt = 0; mt < 32; ++mt) {
    // STEP(JJ): consume (C0,C1,YC); prefetch step JJ+2 into (N0,N1,YN).
#define CHAM_STEP(JJ, NOFF, NY, C0, C1, YC, N0, N1, YN)                       \
    {                                                                         \
      N0 = *(const short8*)(pB + (NOFF));                                     \
      N1 = *(const short8*)(pB + (NOFF) + 512);                               \
      YN = pY[(NY)];                                                          \
      /* acc = xy - x2/2 (C carries exact fp32 -x2/2) */                      \
      float4_t acc[4];                                                        \
      __builtin_amdgcn_s_setprio(1);                                          \
      acc[0] = __builtin_amdgcn_mfma_f32_16x16x32_bf16(afr[0][0], C0, negx2[0], 0, 0, 0); \
      acc[1] = __builtin_amdgcn_mfma_f32_16x16x32_bf16(afr[1][0], C0, negx2[1], 0, 0, 0); \
      acc[2] = __builtin_amdgcn_mfma_f32_16x16x32_bf16(afr[2][0], C0, negx2[2], 0, 0, 0); \
      acc[3] = __builtin_amdgcn_mfma_f32_16x16x32_bf16(afr[3][0], C0, negx2[3], 0, 0, 0); \
      acc[0] = __builtin_amdgcn_mfma_f32_16x16x32_bf16(afr[0][1], C1, acc[0], 0, 0, 0);   \
      acc[1] = __builtin_amdgcn_mfma_f32_16x16x32_bf16(afr[1][1], C1, acc[1], 0, 0, 0);   \
      acc[2] = __builtin_amdgcn_mfma_f32_16x16x32_bf16(afr[2][1], C1, acc[2], 0, 0, 0);   \
      acc[3] = __builtin_amdgcn_mfma_f32_16x16x32_bf16(afr[3][1], C1, acc[3], 0, 0, 0);   \
      __builtin_amdgcn_s_setprio(0);                                          \
      /* col side: max3-fusable triples: 16 values in 8 v_max3/v_max */       \
      float t0 = fmaxf(fmaxf(acc[0][0], acc[0][1]), acc[0][2]);               \
      float t1 = fmaxf(fmaxf(acc[0][3], acc[1][0]), acc[1][1]);               \
      float t2 = fmaxf(fmaxf(acc[1][2], acc[1][3]), acc[2][0]);               \
      float t3 = fmaxf(fmaxf(acc[2][1], acc[2][2]), acc[2][3]);               \
      float t4 = fmaxf(fmaxf(acc[3][0], acc[3][1]), acc[3][2]);               \
      float u0 = fmaxf(fmaxf(t0, t1), t2);                                    \
      float u1 = fmaxf(fmaxf(t3, t4), acc[3][3]);                             \
      float cm = fmaxf(u0, u1);                                               \
      cm = fmaxf(cm, __shfl_xor(cm, 16));                                     \
      cm = fmaxf(cm, __shfl_xor(cm, 32));                                     \
      if (q == 0)                                                             \
        colbuf[wr][moff + wc*64 + (JJ)*16 + l15] = cm;                        \
      /* row side: rowmax = max(acc - y2/2) = -min(d^2)/2 */                  \
      {                                                                       \
        const float y2j = YC;                                                 \
        for (int i_ = 0; i_ < 4; ++i_)                                        \
          for (int r_ = 0; r_ < 4; ++r_)                                      \
            rowmax[i_][r_] = fmaxf(rowmax[i_][r_], acc[i_][r_] - y2j);        \
      }                                                                       \
    }
    // step jj: consume b[jj], load b[(jj+2)&3] = step jj+2
    //   jj=0 -> load tile mt, jj2  (offset 2048)
    //   jj=1 -> load tile mt, jj3  (offset 3072)
    //   jj=2 -> load tile mt+1, jj0 (offset 8192)
    //   jj=3 -> load tile mt+1, jj1 (offset 9216)
    CHAM_STEP(0, 2048,              32,  b0lo, b0hi, y20, b2lo, b2hi, y22)
    CHAM_STEP(1, 3072,              48,  b1lo, b1hi, y21, b3lo, b3hi, y23)
    CHAM_STEP(2, TILE_SHORTS,       128, b2lo, b2hi, y22, b0lo, b0hi, y20)
    CHAM_STEP(3, TILE_SHORTS+1024,  144, b3lo, b3hi, y23, b1lo, b1hi, y21)
#undef CHAM_STEP
    pB += TILE_SHORTS;
    pY += 128;
    moff += 128;
  }

  // ---- row side finalize: shfl over cols (l15), cross-wc via LDS ----
#pragma unroll
  for (int i = 0; i < 4; ++i)
#pragma unroll
    for (int r = 0; r < 4; ++r) {
      float v = rowmax[i][r];
      v = fmaxf(v, __shfl_xor(v, 1));
      v = fmaxf(v, __shfl_xor(v, 2));
      v = fmaxf(v, __shfl_xor(v, 4));
      v = fmaxf(v, __shfl_xor(v, 8));
      rowmax[i][r] = v;
    }
  if (l15 == 0) {
#pragma unroll
    for (int i = 0; i < 4; ++i)
#pragma unroll
      for (int r = 0; r < 4; ++r)
        rowbuf[wc][wr*64 + i*16 + q*4 + r] = rowmax[i][r];
  }
  __syncthreads();   // colbuf planes + rowbuf complete

  if (tid < 128) {
    float v = fmaxf(rowbuf[0][tid], rowbuf[1][tid]);     // -min(d^2)/2
    if (use_part) rowpart[(size_t)((h << 9) | (b << 6) | nt) * 128 + tid] = v;
    else          atomicMax(&rowmax_u[b*NN + n0 + tid], enc_ord(v));
  }

  // ---- col drain: fold wr planes; 16 KB coalesced stores (partial path) ----
  {
    float*    colp = colpart + (size_t)((b << 6) | nt) * NN + (h << 12);
    unsigned* colu = colmax_u + b*NN + (h << 12);
#pragma unroll
    for (int k = 0; k < 16; ++k) {
      const int t = k * 256 + tid;
      const float m = fmaxf(colbuf[0][t], colbuf[1][t]);
      if (use_part) colp[t] = m;
      else          atomicMax(&colu[t], enc_ord(m));
    }
  }
}

// ---------------------------------------------------------------------------
// K3: col combine over 64 nt + sqrt; row combine over 2 h + sqrt; block sum;
// atomicAdd scaled result into out.  [R0 version verbatim]
// ---------------------------------------------------------------------------
__global__ __launch_bounds__(256) void reduce_kernel(
    const float* __restrict__ rowpart, const float* __restrict__ colpart,
    const unsigned* __restrict__ rowmax_u, const unsigned* __restrict__ colmax_u,
    const float* __restrict__ y2h, float* __restrict__ out,
    const int use_part)
{
  const int bid = blockIdx.x;          // 256
  const int tid = threadIdx.x;
  const int g = bid*256 + tid;         // 0..65535
  const int b = g >> 13, m = g & (NN - 1);

  float vc, vr;
  if (use_part) {
    vc = -3.0e38f;
#pragma unroll 8
    for (int nt = 0; nt < 64; ++nt)
      vc = fmaxf(vc, colpart[(size_t)((b << 6) | nt) * NN + m]);
    const int nt = m >> 7, r = m & 127;
    float r0 = rowpart[(size_t)((0 << 9) | (b << 6) | nt) * 128 + r];
    float r1 = rowpart[(size_t)((1 << 9) | (b << 6) | nt) * 128 + r];
    vr = fmaxf(r0, r1);
  } else {
    vc = dec_ord(colmax_u[g]);
    vr = dec_ord(rowmax_u[g]);
  }
  float s = sqrtf(fmaxf(2.f*(y2h[g] - vc), 0.f))   // nearest-x for this y
          + sqrtf(fmaxf(-2.f*vr, 0.f));            // nearest-y for this x

#pragma unroll
  for (int d = 1; d < 64; d <<= 1) s += __shfl_xor(s, d);
  __shared__ float wsum[4];
  if ((tid & 63) == 0) wsum[tid >> 6] = s;
  __syncthreads();
  if (tid == 0)
    atomicAdd(out, (wsum[0] + wsum[1] + wsum[2] + wsum[3]) * (1.0f / 65536.0f));
}

// ---------------------------------------------------------------------------
extern "C" void kernel_launch(void* const* d_in, const int* in_sizes, int n_in,
                              void* d_out, int out_size, void* d_ws, size_t ws_size,
                              hipStream_t stream) {
  const float* x = (const float*)d_in[0];
  const float* y = (const float*)d_in[1];
  float* out = (float*)d_out;

  char* p = (char*)d_ws;
  u16* xs = (u16*)p;            p += (size_t)512 * 16384;   // 8 MiB
  u16* ys = (u16*)p;            p += (size_t)512 * 16384;   // 8 MiB
  float* x2h = (float*)p;       p += (size_t)65536 * 4;
  float* y2h = (float*)p;       p += (size_t)65536 * 4;
  char* tail = p;
  // partial path: colpart 16 MiB + rowpart 512 KiB  (33 MiB total — proven
  // to fit in R0; R9's 49 MiB overflowed and fell back to atomics)
  float* colpart = (float*)tail;
  float* rowpart = (float*)(tail + (size_t)512 * 8192 * 4);
  // atomic fallback: two 256 KiB ordered-uint max buffers
  unsigned* colmax_u = (unsigned*)tail;
  unsigned* rowmax_u = (unsigned*)(tail + (size_t)65536 * 4);
  const size_t need_part = (size_t)(tail - (char*)d_ws) +
                           (size_t)512 * 8192 * 4 + (size_t)1024 * 128 * 4;
  const int use_part = (ws_size >= need_part) ? 1 : 0;

  pre_kernel<<<dim3(1024), dim3(256), 0, stream>>>(x, y, xs, ys, x2h, y2h,
                                                   rowmax_u, colmax_u, out,
                                                   use_part);
  main_kernel<<<dim3(1024), dim3(256), 0, stream>>>(xs, ys, x2h, y2h,
                                                    rowpart, colpart,
                                                    rowmax_u, colmax_u,
                                                    use_part);
  reduce_kernel<<<dim3(256), dim3(256), 0, stream>>>(rowpart, colpart,
                                                     rowmax_u, colmax_u, y2h,
                                                     out, use_part);
}

// Round 7
// 171.866 us; speedup vs baseline: 2.7254x; 1.0555x over previous
//
#include <hip/hip_runtime.h>
#include <cstdint>
#include <cstddef>

typedef unsigned short u16;
typedef __attribute__((ext_vector_type(8))) short short8;
typedef __attribute__((ext_vector_type(8))) u16 ushort8;
typedef __attribute__((ext_vector_type(4))) float float4_t;

#define BB 8
#define NN 8192
#define DD 64
#define TILE_SHORTS 8192     // 128 points * 64 k (bf16)
#define LDS_STRIDE 68        // 64 floats + 4 pad (bank spread)

__device__ inline u16 f32_to_bf16(float f) {
  unsigned u = __float_as_uint(f);
  u += 0x7FFFu + ((u >> 16) & 1u);   // RNE
  return (u16)(u >> 16);
}

__device__ inline unsigned enc_ord(float f) {
  unsigned u = __float_as_uint(f);
  return (u & 0x80000000u) ? ~u : (u | 0x80000000u);
}
__device__ inline float dec_ord(unsigned u) {
  return __uint_as_float((u & 0x80000000u) ? (u & 0x7fffffffu) : ~u);
}

// ---------------------------------------------------------------------------
// K1: one block = one 128x64 tile. Coalesced read-once -> LDS -> swizzled
// bf16 tile (MFMA fragment chunk order) + 0.5*|row|^2.  [verified R6/R7]
// R15 delta: rowmax_u is zero-inited ALWAYS (rows now use end-of-kernel
// atomics in both paths); colmax_u only in the fallback path.
// ---------------------------------------------------------------------------
__global__ __launch_bounds__(256) void pre_kernel(
    const float* __restrict__ x, const float* __restrict__ y,
    u16* __restrict__ xs, u16* __restrict__ ys,
    float* __restrict__ x2h, float* __restrict__ y2h,
    unsigned* __restrict__ rowmax_u, unsigned* __restrict__ colmax_u,
    float* __restrict__ out, const int use_part)
{
  __shared__ float stage[128 * LDS_STRIDE];   // 34 KB

  const int bid = blockIdx.x;          // 1024: 0..511 -> x, 512..1023 -> y
  const int tid = threadIdx.x;

  if (bid >= 256 && bid < 512) rowmax_u[((bid - 256) << 8) | tid] = 0u;
  if (!use_part && bid < 256)  colmax_u[(bid << 8) | tid] = 0u;
  if (bid == 0 && tid == 0) out[0] = 0.f;

  const bool isY = bid >= 512;
  const int t = bid & 511;             // tile id = b*64 + nt
  const float* src = (isY ? y : x) + (size_t)t * (128 * DD);
  u16* dst = (isY ? ys : xs) + (size_t)t * TILE_SHORTS;
  float* s2 = (isY ? y2h : x2h) + t * 128;

#pragma unroll
  for (int c = 0; c < 8; ++c) {
    const int idx = c * 256 + tid;     // float4 index within tile (0..2047)
    float4 f = ((const float4*)src)[idx];
    const int r = idx >> 4, kc = idx & 15;
    *(float4*)&stage[r * LDS_STRIDE + kc * 4] = f;
  }
  __syncthreads();

  {
    const int r = tid >> 1, half = tid & 1;
    const float* rp = &stage[r * LDS_STRIDE + half * 32];
    float ss = 0.f;
#pragma unroll
    for (int k = 0; k < 8; ++k) {
      float4 f = *(const float4*)&rp[k * 4];
      ss += f.x*f.x + f.y*f.y + f.z*f.z + f.w*f.w;
    }
    ss += __shfl_xor(ss, 1);
    if (half == 0) s2[r] = 0.5f * ss;
  }

  {
    const int w = tid >> 6, lane = tid & 63;
    const int qq = lane >> 4, rl = lane & 15;
#pragma unroll
    for (int u = 0; u < 4; ++u) {
      const int chunk = w * 4 + u;
      const int I = chunk >> 1, s = chunk & 1;
      const float* rp = &stage[(I*16 + rl) * LDS_STRIDE + s*32 + qq*8];
      ushort8 o;
#pragma unroll
      for (int j = 0; j < 8; ++j) o[j] = f32_to_bf16(rp[j]);
      *(ushort8*)(dst + chunk*512 + lane*8) = o;
    }
  }
}

// ---------------------------------------------------------------------------
// K2: main — R15.  Ledger: R0 90us (256,2); R12=R14 100us (256,3, grid
// 1024). All sustain the SAME avg 8 waves/CU: grid 1024 at 3/CU runs
// phases 3-then-1 (avg 2/CU, occ 24.6% ✓), at 2/CU runs 2 clean phases
// (avg 2/CU). (256,4) twice-proven poison. The lever left: DIVISIBILITY.
// R15: grid 2048 = h(2b quarter-cols) | nt(6) | b(3), 16 col-tiles/block,
// (256,3). Fluid wall ~ (2048/768) * T_quarter ~ 1.33 * T_half vs 2.0.
// Row partials no longer fit a partial buffer at this grid -> rows go
// through END-OF-KERNEL atomicMax ALWAYS (262K lane-atomics = ~4K wave
// insts chip-wide, trivial — R9's disaster was 2M IN-LOOP col atomics).
// rowpart deleted: need_part = 16.5 + 16 (colpart unchanged; h-blocks
// write disjoint col ranges) + 0.25 MiB = 32.75 MiB < R0-proven 33.0.
// Inner loop = R14's proven depth-2 4-buffer pipeline, verbatim.
// R3/R4/R6/R8 bans respected: C-init carries -x2/2, jj-sequential acc.
// ---------------------------------------------------------------------------
__global__ __launch_bounds__(256, 3) void main_kernel(
    const u16* __restrict__ xs, const u16* __restrict__ ys,
    const float* __restrict__ x2h, const float* __restrict__ y2h,
    float* __restrict__ colpart,
    unsigned* __restrict__ rowmax_u, unsigned* __restrict__ colmax_u,
    const int use_part)
{
  __shared__ float colbuf[2][2048];    // 16 KB: [wr][mt*128 + col]
  __shared__ float rowbuf[2][128];     // [wc][row]

  const int bid = blockIdx.x;            // 2048
  const int b   = bid & 7;               // XCD-affine
  const int nt  = (bid >> 3) & 63;
  const int h   = bid >> 9;              // 0..3 column quarter
  const int tid = threadIdx.x;
  const int w = tid >> 6, lane = tid & 63;
  const int wr = w >> 1, wc = w & 1;     // row-half / col-half owner
  const int l15 = lane & 15, q = lane >> 4;
  const int n0 = nt << 7;
  const int mt_start = h << 4;           // 16 col-tiles per block

  // ---- A fragments: this wave's 64 rows, both K-halves ----
  const u16* xs_tile = xs + (size_t)((b << 6) | nt) * TILE_SHORTS;
  short8 afr[4][2];
#pragma unroll
  for (int i = 0; i < 4; ++i)
#pragma unroll
    for (int s = 0; s < 2; ++s)
      afr[i][s] = *(const short8*)(xs_tile + ((wr*4 + i)*2 + s)*512 + lane*8);

  // ---- C-init quads: -x2/2 per row (fp32 exact) ----
  float4_t negx2[4];
  const float* x2b = x2h + b*NN + n0 + wr*64;
#pragma unroll
  for (int i = 0; i < 4; ++i) {
    float4_t v = *(const float4_t*)(x2b + i*16 + q*4);
    negx2[i] = {-v[0], -v[1], -v[2], -v[3]};
  }

  float rowmax[4][4];
#pragma unroll
  for (int i = 0; i < 4; ++i)
#pragma unroll
    for (int r = 0; r < 4; ++r) rowmax[i][r] = -3.0e38f;

  // ---- pointer-bumped streams; imm offsets cover the chunk loads ----
  const u16*  pB = ys + (size_t)((b << 6) + mt_start) * TILE_SHORTS
                   + wc*4096 + lane*8;
  const float* pY = y2h + b*NN + mt_start*128 + wc*64 + l15;

  // ---- depth-2 pipeline, 4 static buffers: step jj consumes bJJ, loads
  //      b[(jj+2)&3]. Prologue fills b0 (tile0,jj0) and b1 (tile0,jj1). ----
  short8 b0lo, b0hi, b1lo, b1hi, b2lo, b2hi, b3lo, b3hi;
  float  y20, y21, y22, y23;
  b0lo = *(const short8*)(pB);
  b0hi = *(const short8*)(pB + 512);
  y20  = pY[0];
  b1lo = *(const short8*)(pB + 1024);
  b1hi = *(const short8*)(pB + 1536);
  y21  = pY[16];

  int moff = 0;
  for (int mt = 0; mt < 16; ++mt) {
    // STEP(JJ): consume (C0,C1,YC); prefetch step JJ+2 into (N0,N1,YN).
#define CHAM_STEP(JJ, NOFF, NY, C0, C1, YC, N0, N1, YN)                       \
    {                                                                         \
      N0 = *(const short8*)(pB + (NOFF));                                     \
      N1 = *(const short8*)(pB + (NOFF) + 512);                               \
      YN = pY[(NY)];                                                          \
      /* acc = xy - x2/2 (C carries exact fp32 -x2/2) */                      \
      float4_t acc[4];                                                        \
      __builtin_amdgcn_s_setprio(1);                                          \
      acc[0] = __builtin_amdgcn_mfma_f32_16x16x32_bf16(afr[0][0], C0, negx2[0], 0, 0, 0); \
      acc[1] = __builtin_amdgcn_mfma_f32_16x16x32_bf16(afr[1][0], C0, negx2[1], 0, 0, 0); \
      acc[2] = __builtin_amdgcn_mfma_f32_16x16x32_bf16(afr[2][0], C0, negx2[2], 0, 0, 0); \
      acc[3] = __builtin_amdgcn_mfma_f32_16x16x32_bf16(afr[3][0], C0, negx2[3], 0, 0, 0); \
      acc[0] = __builtin_amdgcn_mfma_f32_16x16x32_bf16(afr[0][1], C1, acc[0], 0, 0, 0);   \
      acc[1] = __builtin_amdgcn_mfma_f32_16x16x32_bf16(afr[1][1], C1, acc[1], 0, 0, 0);   \
      acc[2] = __builtin_amdgcn_mfma_f32_16x16x32_bf16(afr[2][1], C1, acc[2], 0, 0, 0);   \
      acc[3] = __builtin_amdgcn_mfma_f32_16x16x32_bf16(afr[3][1], C1, acc[3], 0, 0, 0);   \
      __builtin_amdgcn_s_setprio(0);                                          \
      /* col side: max3-fusable triples: 16 values in 8 v_max3/v_max */       \
      float t0 = fmaxf(fmaxf(acc[0][0], acc[0][1]), acc[0][2]);               \
      float t1 = fmaxf(fmaxf(acc[0][3], acc[1][0]), acc[1][1]);               \
      float t2 = fmaxf(fmaxf(acc[1][2], acc[1][3]), acc[2][0]);               \
      float t3 = fmaxf(fmaxf(acc[2][1], acc[2][2]), acc[2][3]);               \
      float t4 = fmaxf(fmaxf(acc[3][0], acc[3][1]), acc[3][2]);               \
      float u0 = fmaxf(fmaxf(t0, t1), t2);                                    \
      float u1 = fmaxf(fmaxf(t3, t4), acc[3][3]);                             \
      float cm = fmaxf(u0, u1);                                               \
      cm = fmaxf(cm, __shfl_xor(cm, 16));                                     \
      cm = fmaxf(cm, __shfl_xor(cm, 32));                                     \
      if (q == 0)                                                             \
        colbuf[wr][moff + wc*64 + (JJ)*16 + l15] = cm;                        \
      /* row side: rowmax = max(acc - y2/2) = -min(d^2)/2 */                  \
      {                                                                       \
        const float y2j = YC;                                                 \
        for (int i_ = 0; i_ < 4; ++i_)                                        \
          for (int r_ = 0; r_ < 4; ++r_)                                      \
            rowmax[i_][r_] = fmaxf(rowmax[i_][r_], acc[i_][r_] - y2j);        \
      }                                                                       \
    }
    // step jj: consume b[jj], load b[(jj+2)&3] = step jj+2
    CHAM_STEP(0, 2048,              32,  b0lo, b0hi, y20, b2lo, b2hi, y22)
    CHAM_STEP(1, 3072,              48,  b1lo, b1hi, y21, b3lo, b3hi, y23)
    CHAM_STEP(2, TILE_SHORTS,       128, b2lo, b2hi, y22, b0lo, b0hi, y20)
    CHAM_STEP(3, TILE_SHORTS+1024,  144, b3lo, b3hi, y23, b1lo, b1hi, y21)
#undef CHAM_STEP
    pB += TILE_SHORTS;
    pY += 128;
    moff += 128;
  }

  // ---- row side finalize: shfl over cols (l15), cross-wc via LDS ----
#pragma unroll
  for (int i = 0; i < 4; ++i)
#pragma unroll
    for (int r = 0; r < 4; ++r) {
      float v = rowmax[i][r];
      v = fmaxf(v, __shfl_xor(v, 1));
      v = fmaxf(v, __shfl_xor(v, 2));
      v = fmaxf(v, __shfl_xor(v, 4));
      v = fmaxf(v, __shfl_xor(v, 8));
      rowmax[i][r] = v;
    }
  if (l15 == 0) {
#pragma unroll
    for (int i = 0; i < 4; ++i)
#pragma unroll
      for (int r = 0; r < 4; ++r)
        rowbuf[wc][wr*64 + i*16 + q*4 + r] = rowmax[i][r];
  }
  __syncthreads();   // colbuf planes + rowbuf complete

  // rows: one end-of-kernel device atomic per row (both paths)
  if (tid < 128) {
    float v = fmaxf(rowbuf[0][tid], rowbuf[1][tid]);     // -min(d^2)/2
    atomicMax(&rowmax_u[b*NN + n0 + tid], enc_ord(v));
  }

  // ---- col drain: fold wr planes; 8 KB coalesced stores (partial path) ----
  {
    float*    colp = colpart + (size_t)((b << 6) | nt) * NN + (h << 11);
    unsigned* colu = colmax_u + b*NN + (h << 11);
#pragma unroll
    for (int k = 0; k < 8; ++k) {
      const int t = k * 256 + tid;
      const float m = fmaxf(colbuf[0][t], colbuf[1][t]);
      if (use_part) colp[t] = m;
      else          atomicMax(&colu[t], enc_ord(m));
    }
  }
}

// ---------------------------------------------------------------------------
// K3: col combine over 64 nt + sqrt; rows from rowmax_u (always atomic) +
// sqrt; block sum; atomicAdd scaled result into out.
// ---------------------------------------------------------------------------
__global__ __launch_bounds__(256) void reduce_kernel(
    const float* __restrict__ colpart,
    const unsigned* __restrict__ rowmax_u, const unsigned* __restrict__ colmax_u,
    const float* __restrict__ y2h, float* __restrict__ out,
    const int use_part)
{
  const int bid = blockIdx.x;          // 256
  const int tid = threadIdx.x;
  const int g = bid*256 + tid;         // 0..65535
  const int b = g >> 13, m = g & (NN - 1);

  float vc;
  if (use_part) {
    vc = -3.0e38f;
#pragma unroll 8
    for (int nt = 0; nt < 64; ++nt)
      vc = fmaxf(vc, colpart[(size_t)((b << 6) | nt) * NN + m]);
  } else {
    vc = dec_ord(colmax_u[g]);
  }
  float vr = dec_ord(rowmax_u[g]);
  float s = sqrtf(fmaxf(2.f*(y2h[g] - vc), 0.f))   // nearest-x for this y
          + sqrtf(fmaxf(-2.f*vr, 0.f));            // nearest-y for this x

#pragma unroll
  for (int d = 1; d < 64; d <<= 1) s += __shfl_xor(s, d);
  __shared__ float wsum[4];
  if ((tid & 63) == 0) wsum[tid >> 6] = s;
  __syncthreads();
  if (tid == 0)
    atomicAdd(out, (wsum[0] + wsum[1] + wsum[2] + wsum[3]) * (1.0f / 65536.0f));
}

// ---------------------------------------------------------------------------
extern "C" void kernel_launch(void* const* d_in, const int* in_sizes, int n_in,
                              void* d_out, int out_size, void* d_ws, size_t ws_size,
                              hipStream_t stream) {
  const float* x = (const float*)d_in[0];
  const float* y = (const float*)d_in[1];
  float* out = (float*)d_out;

  char* p = (char*)d_ws;
  u16* xs = (u16*)p;            p += (size_t)512 * 16384;   // 8 MiB
  u16* ys = (u16*)p;            p += (size_t)512 * 16384;   // 8 MiB
  float* x2h = (float*)p;       p += (size_t)65536 * 4;
  float* y2h = (float*)p;       p += (size_t)65536 * 4;
  char* tail = p;
  // partial path: colpart 16 MiB, then rowmax_u 256 KiB.
  // need = 16.5 + 16 + 0.25 = 32.75 MiB  (< R0-proven 33.0 MiB)
  float* colpart = (float*)tail;
  // atomic fallback: colmax_u at tail, rowmax_u right after (512 KiB total)
  unsigned* colmax_u = (unsigned*)tail;
  const size_t need_part = (size_t)(tail - (char*)d_ws) +
                           (size_t)512 * 8192 * 4 + (size_t)65536 * 4;
  const int use_part = (ws_size >= need_part) ? 1 : 0;
  unsigned* rowmax_u = use_part
      ? (unsigned*)(tail + (size_t)512 * 8192 * 4)
      : (unsigned*)(tail + (size_t)65536 * 4);

  pre_kernel<<<dim3(1024), dim3(256), 0, stream>>>(x, y, xs, ys, x2h, y2h,
                                                   rowmax_u, colmax_u, out,
                                                   use_part);
  main_kernel<<<dim3(2048), dim3(256), 0, stream>>>(xs, ys, x2h, y2h,
                                                    colpart,
                                                    rowmax_u, colmax_u,
                                                    use_part);
  reduce_kernel<<<dim3(256), dim3(256), 0, stream>>>(colpart,
                                                     rowmax_u, colmax_u, y2h,
                                                     out, use_part);
}

// Round 8
// 157.338 us; speedup vs baseline: 2.9771x; 1.0923x over previous
//
#include <hip/hip_runtime.h>
#include <cstdint>
#include <cstddef>

typedef unsigned short u16;
typedef __attribute__((ext_vector_type(8))) short short8;
typedef __attribute__((ext_vector_type(8))) u16 ushort8;
typedef __attribute__((ext_vector_type(4))) float float4_t;

#define BB 8
#define NN 8192
#define DD 64
#define TILE_SHORTS 8192     // 128 points * 64 k (bf16)
#define LDS_STRIDE 68        // 64 floats + 4 pad (bank spread)

__device__ inline u16 f32_to_bf16(float f) {
  unsigned u = __float_as_uint(f);
  u += 0x7FFFu + ((u >> 16) & 1u);   // RNE
  return (u16)(u >> 16);
}

__device__ inline unsigned enc_ord(float f) {
  unsigned u = __float_as_uint(f);
  return (u & 0x80000000u) ? ~u : (u | 0x80000000u);
}
__device__ inline float dec_ord(unsigned u) {
  return __uint_as_float((u & 0x80000000u) ? (u & 0x7fffffffu) : ~u);
}

// ---------------------------------------------------------------------------
// K1: one block = one 128x64 tile. Coalesced read-once -> LDS -> swizzled
// bf16 tile (MFMA fragment chunk order) + 0.5*|row|^2.  [verified R6/R7]
// rowmax_u zero-inited ALWAYS (rows use end-of-kernel atomics both paths);
// colmax_u only in the fallback path.
// ---------------------------------------------------------------------------
__global__ __launch_bounds__(256) void pre_kernel(
    const float* __restrict__ x, const float* __restrict__ y,
    u16* __restrict__ xs, u16* __restrict__ ys,
    float* __restrict__ x2h, float* __restrict__ y2h,
    unsigned* __restrict__ rowmax_u, unsigned* __restrict__ colmax_u,
    float* __restrict__ out, const int use_part)
{
  __shared__ float stage[128 * LDS_STRIDE];   // 34 KB

  const int bid = blockIdx.x;          // 1024: 0..511 -> x, 512..1023 -> y
  const int tid = threadIdx.x;

  if (bid >= 256 && bid < 512) rowmax_u[((bid - 256) << 8) | tid] = 0u;
  if (!use_part && bid < 256)  colmax_u[(bid << 8) | tid] = 0u;
  if (bid == 0 && tid == 0) out[0] = 0.f;

  const bool isY = bid >= 512;
  const int t = bid & 511;             // tile id = b*64 + nt
  const float* src = (isY ? y : x) + (size_t)t * (128 * DD);
  u16* dst = (isY ? ys : xs) + (size_t)t * TILE_SHORTS;
  float* s2 = (isY ? y2h : x2h) + t * 128;

#pragma unroll
  for (int c = 0; c < 8; ++c) {
    const int idx = c * 256 + tid;     // float4 index within tile (0..2047)
    float4 f = ((const float4*)src)[idx];
    const int r = idx >> 4, kc = idx & 15;
    *(float4*)&stage[r * LDS_STRIDE + kc * 4] = f;
  }
  __syncthreads();

  {
    const int r = tid >> 1, half = tid & 1;
    const float* rp = &stage[r * LDS_STRIDE + half * 32];
    float ss = 0.f;
#pragma unroll
    for (int k = 0; k < 8; ++k) {
      float4 f = *(const float4*)&rp[k * 4];
      ss += f.x*f.x + f.y*f.y + f.z*f.z + f.w*f.w;
    }
    ss += __shfl_xor(ss, 1);
    if (half == 0) s2[r] = 0.5f * ss;
  }

  {
    const int w = tid >> 6, lane = tid & 63;
    const int qq = lane >> 4, rl = lane & 15;
#pragma unroll
    for (int u = 0; u < 4; ++u) {
      const int chunk = w * 4 + u;
      const int I = chunk >> 1, s = chunk & 1;
      const float* rp = &stage[(I*16 + rl) * LDS_STRIDE + s*32 + qq*8];
      ushort8 o;
#pragma unroll
      for (int j = 0; j < 8; ++j) o[j] = f32_to_bf16(rp[j]);
      *(ushort8*)(dst + chunk*512 + lane*8) = o;
    }
  }
}

// ---------------------------------------------------------------------------
// K2: main — R16.  R15 (91.5us, best) analysis: MfmaUtil 31 + true-VALU
// ~22 -> ~45% of cycles NO pipe issues at 2.3 waves/SIMD = per-wave
// LATENCY. Per-jj critical path audit: the q-fold's TWO DEPENDENT
// __shfl_xor ops are DS-pipe round trips (~60-120 cyc dependent latency
// each, m117) = ~200+ cyc/jj of cross-lane wait x4 per mt. That is why
// neither occupancy (R15) nor prefetch depth (R14) moved MfmaUtil.
// R16 deletes the in-loop cross-lane fold: all 64 lanes push their
// 16-row partial via FIRE-AND-FORGET LDS atomicMax (ds_max_u32, result
// unused -> no wave-visible wait) into ONE shared ordered-uint plane
// colbufu[2048] (merges wr planes, kills q-divergence). 4-way
// same-address within a wave ~1.6x on LDS pipe (m136) — pipe load
// trivial. Init 8KB + barrier before loop; pre-drain __syncthreads
// (compiler emits lgkmcnt(0) before s_barrier) orders the atomics.
// Bit-exact: enc_ord is order-isomorphic, every slot gets all 128 rows.
// Everything else R15-verbatim (geometry 2048=h4|nt|b, depth-2 4-buffer
// pipeline, row side, 32.75 MiB workspace). (256,4) ban stands.
// ---------------------------------------------------------------------------
__global__ __launch_bounds__(256, 3) void main_kernel(
    const u16* __restrict__ xs, const u16* __restrict__ ys,
    const float* __restrict__ x2h, const float* __restrict__ y2h,
    float* __restrict__ colpart,
    unsigned* __restrict__ rowmax_u, unsigned* __restrict__ colmax_u,
    const int use_part)
{
  __shared__ unsigned colbufu[2048];   // 8 KB: [mt*128 + col], enc_ord
  __shared__ float rowbuf[2][128];     // [wc][row]

  const int bid = blockIdx.x;            // 2048
  const int b   = bid & 7;               // XCD-affine
  const int nt  = (bid >> 3) & 63;
  const int h   = bid >> 9;              // 0..3 column quarter
  const int tid = threadIdx.x;
  const int w = tid >> 6, lane = tid & 63;
  const int wr = w >> 1, wc = w & 1;     // row-half / col-half owner
  const int l15 = lane & 15, q = lane >> 4;
  const int n0 = nt << 7;
  const int mt_start = h << 4;           // 16 col-tiles per block

  // colbufu init: 0u is below enc_ord of every finite float
#pragma unroll
  for (int k = 0; k < 8; ++k) colbufu[k * 256 + tid] = 0u;

  // ---- A fragments: this wave's 64 rows, both K-halves ----
  const u16* xs_tile = xs + (size_t)((b << 6) | nt) * TILE_SHORTS;
  short8 afr[4][2];
#pragma unroll
  for (int i = 0; i < 4; ++i)
#pragma unroll
    for (int s = 0; s < 2; ++s)
      afr[i][s] = *(const short8*)(xs_tile + ((wr*4 + i)*2 + s)*512 + lane*8);

  // ---- C-init quads: -x2/2 per row (fp32 exact) ----
  float4_t negx2[4];
  const float* x2b = x2h + b*NN + n0 + wr*64;
#pragma unroll
  for (int i = 0; i < 4; ++i) {
    float4_t v = *(const float4_t*)(x2b + i*16 + q*4);
    negx2[i] = {-v[0], -v[1], -v[2], -v[3]};
  }

  float rowmax[4][4];
#pragma unroll
  for (int i = 0; i < 4; ++i)
#pragma unroll
    for (int r = 0; r < 4; ++r) rowmax[i][r] = -3.0e38f;

  // ---- pointer-bumped streams; imm offsets cover the chunk loads ----
  const u16*  pB = ys + (size_t)((b << 6) + mt_start) * TILE_SHORTS
                   + wc*4096 + lane*8;
  const float* pY = y2h + b*NN + mt_start*128 + wc*64 + l15;

  // ---- depth-2 pipeline, 4 static buffers: step jj consumes bJJ, loads
  //      b[(jj+2)&3]. Prologue fills b0 (tile0,jj0) and b1 (tile0,jj1). ----
  short8 b0lo, b0hi, b1lo, b1hi, b2lo, b2hi, b3lo, b3hi;
  float  y20, y21, y22, y23;
  b0lo = *(const short8*)(pB);
  b0hi = *(const short8*)(pB + 512);
  y20  = pY[0];
  b1lo = *(const short8*)(pB + 1024);
  b1hi = *(const short8*)(pB + 1536);
  y21  = pY[16];

  __syncthreads();                       // colbufu init visible to all waves

  int moff = 0;
  for (int mt = 0; mt < 16; ++mt) {
    // STEP(JJ): consume (C0,C1,YC); prefetch step JJ+2 into (N0,N1,YN).
#define CHAM_STEP(JJ, NOFF, NY, C0, C1, YC, N0, N1, YN)                       \
    {                                                                         \
      N0 = *(const short8*)(pB + (NOFF));                                     \
      N1 = *(const short8*)(pB + (NOFF) + 512);                               \
      YN = pY[(NY)];                                                          \
      /* acc = xy - x2/2 (C carries exact fp32 -x2/2) */                      \
      float4_t acc[4];                                                        \
      __builtin_amdgcn_s_setprio(1);                                          \
      acc[0] = __builtin_amdgcn_mfma_f32_16x16x32_bf16(afr[0][0], C0, negx2[0], 0, 0, 0); \
      acc[1] = __builtin_amdgcn_mfma_f32_16x16x32_bf16(afr[1][0], C0, negx2[1], 0, 0, 0); \
      acc[2] = __builtin_amdgcn_mfma_f32_16x16x32_bf16(afr[2][0], C0, negx2[2], 0, 0, 0); \
      acc[3] = __builtin_amdgcn_mfma_f32_16x16x32_bf16(afr[3][0], C0, negx2[3], 0, 0, 0); \
      acc[0] = __builtin_amdgcn_mfma_f32_16x16x32_bf16(afr[0][1], C1, acc[0], 0, 0, 0);   \
      acc[1] = __builtin_amdgcn_mfma_f32_16x16x32_bf16(afr[1][1], C1, acc[1], 0, 0, 0);   \
      acc[2] = __builtin_amdgcn_mfma_f32_16x16x32_bf16(afr[2][1], C1, acc[2], 0, 0, 0);   \
      acc[3] = __builtin_amdgcn_mfma_f32_16x16x32_bf16(afr[3][1], C1, acc[3], 0, 0, 0);   \
      __builtin_amdgcn_s_setprio(0);                                          \
      /* col side: in-lane 16-row max tree, then ONE fire-and-forget LDS   */ \
      /* ds_max_u32 — no cross-lane wait on the wave's critical path.      */ \
      float t0 = fmaxf(fmaxf(acc[0][0], acc[0][1]), acc[0][2]);               \
      float t1 = fmaxf(fmaxf(acc[0][3], acc[1][0]), acc[1][1]);               \
      float t2 = fmaxf(fmaxf(acc[1][2], acc[1][3]), acc[2][0]);               \
      float t3 = fmaxf(fmaxf(acc[2][1], acc[2][2]), acc[2][3]);               \
      float t4 = fmaxf(fmaxf(acc[3][0], acc[3][1]), acc[3][2]);               \
      float u0 = fmaxf(fmaxf(t0, t1), t2);                                    \
      float u1 = fmaxf(fmaxf(t3, t4), acc[3][3]);                             \
      float cm = fmaxf(u0, u1);                                               \
      atomicMax(&colbufu[moff + wc*64 + (JJ)*16 + l15], enc_ord(cm));         \
      /* row side: rowmax = max(acc - y2/2) = -min(d^2)/2 */                  \
      {                                                                       \
        const float y2j = YC;                                                 \
        for (int i_ = 0; i_ < 4; ++i_)                                        \
          for (int r_ = 0; r_ < 4; ++r_)                                      \
            rowmax[i_][r_] = fmaxf(rowmax[i_][r_], acc[i_][r_] - y2j);        \
      }                                                                       \
    }
    // step jj: consume b[jj], load b[(jj+2)&3] = step jj+2
    CHAM_STEP(0, 2048,              32,  b0lo, b0hi, y20, b2lo, b2hi, y22)
    CHAM_STEP(1, 3072,              48,  b1lo, b1hi, y21, b3lo, b3hi, y23)
    CHAM_STEP(2, TILE_SHORTS,       128, b2lo, b2hi, y22, b0lo, b0hi, y20)
    CHAM_STEP(3, TILE_SHORTS+1024,  144, b3lo, b3hi, y23, b1lo, b1hi, y21)
#undef CHAM_STEP
    pB += TILE_SHORTS;
    pY += 128;
    moff += 128;
  }

  // ---- row side finalize: shfl over cols (l15), cross-wc via LDS ----
#pragma unroll
  for (int i = 0; i < 4; ++i)
#pragma unroll
    for (int r = 0; r < 4; ++r) {
      float v = rowmax[i][r];
      v = fmaxf(v, __shfl_xor(v, 1));
      v = fmaxf(v, __shfl_xor(v, 2));
      v = fmaxf(v, __shfl_xor(v, 4));
      v = fmaxf(v, __shfl_xor(v, 8));
      rowmax[i][r] = v;
    }
  if (l15 == 0) {
#pragma unroll
    for (int i = 0; i < 4; ++i)
#pragma unroll
      for (int r = 0; r < 4; ++r)
        rowbuf[wc][wr*64 + i*16 + q*4 + r] = rowmax[i][r];
  }
  __syncthreads();   // colbufu atomics + rowbuf complete (lgkmcnt-drained)

  // rows: one end-of-kernel device atomic per row (both paths)
  if (tid < 128) {
    float v = fmaxf(rowbuf[0][tid], rowbuf[1][tid]);     // -min(d^2)/2
    atomicMax(&rowmax_u[b*NN + n0 + tid], enc_ord(v));
  }

  // ---- col drain: decode single plane; 8 KB coalesced (partial path) ----
  {
    float*    colp = colpart + (size_t)((b << 6) | nt) * NN + (h << 11);
    unsigned* colu = colmax_u + b*NN + (h << 11);
#pragma unroll
    for (int k = 0; k < 8; ++k) {
      const int t = k * 256 + tid;
      const unsigned e = colbufu[t];
      if (use_part) colp[t] = dec_ord(e);
      else          atomicMax(&colu[t], e);
    }
  }
}

// ---------------------------------------------------------------------------
// K3: col combine over 64 nt + sqrt; rows from rowmax_u (always atomic) +
// sqrt; block sum; atomicAdd scaled result into out.
// ---------------------------------------------------------------------------
__global__ __launch_bounds__(256) void reduce_kernel(
    const float* __restrict__ colpart,
    const unsigned* __restrict__ rowmax_u, const unsigned* __restrict__ colmax_u,
    const float* __restrict__ y2h, float* __restrict__ out,
    const int use_part)
{
  const int bid = blockIdx.x;          // 256
  const int tid = threadIdx.x;
  const int g = bid*256 + tid;         // 0..65535
  const int b = g >> 13, m = g & (NN - 1);

  float vc;
  if (use_part) {
    vc = -3.0e38f;
#pragma unroll 8
    for (int nt = 0; nt < 64; ++nt)
      vc = fmaxf(vc, colpart[(size_t)((b << 6) | nt) * NN + m]);
  } else {
    vc = dec_ord(colmax_u[g]);
  }
  float vr = dec_ord(rowmax_u[g]);
  float s = sqrtf(fmaxf(2.f*(y2h[g] - vc), 0.f))   // nearest-x for this y
          + sqrtf(fmaxf(-2.f*vr, 0.f));            // nearest-y for this x

#pragma unroll
  for (int d = 1; d < 64; d <<= 1) s += __shfl_xor(s, d);
  __shared__ float wsum[4];
  if ((tid & 63) == 0) wsum[tid >> 6] = s;
  __syncthreads();
  if (tid == 0)
    atomicAdd(out, (wsum[0] + wsum[1] + wsum[2] + wsum[3]) * (1.0f / 65536.0f));
}

// ---------------------------------------------------------------------------
extern "C" void kernel_launch(void* const* d_in, const int* in_sizes, int n_in,
                              void* d_out, int out_size, void* d_ws, size_t ws_size,
                              hipStream_t stream) {
  const float* x = (const float*)d_in[0];
  const float* y = (const float*)d_in[1];
  float* out = (float*)d_out;

  char* p = (char*)d_ws;
  u16* xs = (u16*)p;            p += (size_t)512 * 16384;   // 8 MiB
  u16* ys = (u16*)p;            p += (size_t)512 * 16384;   // 8 MiB
  float* x2h = (float*)p;       p += (size_t)65536 * 4;
  float* y2h = (float*)p;       p += (size_t)65536 * 4;
  char* tail = p;
  // partial path: colpart 16 MiB, then rowmax_u 256 KiB.
  // need = 16.5 + 16 + 0.25 = 32.75 MiB  (< R0-proven 33.0 MiB)
  float* colpart = (float*)tail;
  // atomic fallback: colmax_u at tail, rowmax_u right after (512 KiB total)
  unsigned* colmax_u = (unsigned*)tail;
  const size_t need_part = (size_t)(tail - (char*)d_ws) +
                           (size_t)512 * 8192 * 4 + (size_t)65536 * 4;
  const int use_part = (ws_size >= need_part) ? 1 : 0;
  unsigned* rowmax_u = use_part
      ? (unsigned*)(tail + (size_t)512 * 8192 * 4)
      : (unsigned*)(tail + (size_t)65536 * 4);

  pre_kernel<<<dim3(1024), dim3(256), 0, stream>>>(x, y, xs, ys, x2h, y2h,
                                                   rowmax_u, colmax_u, out,
                                                   use_part);
  main_kernel<<<dim3(2048), dim3(256), 0, stream>>>(xs, ys, x2h, y2h,
                                                    colpart,
                                                    rowmax_u, colmax_u,
                                                    use_part);
  reduce_kernel<<<dim3(256), dim3(256), 0, stream>>>(colpart,
                                                     rowmax_u, colmax_u, y2h,
                                                     out, use_part);
}